// Round 9
// baseline (11528.518 us; speedup 1.0000x reference)
//
#include <hip/hip_runtime.h>
#include <hip/hip_cooperative_groups.h>
#include <math.h>

namespace cg = cooperative_groups;

#define NN 2048
#define NB 4
#define ROWS (NB*NN)   // 8192

// u' = u * S, v' = v * S, with S = log2(e)/eps. Then
// exp((-C+u+v)/eps) = exp2(-S*C + u' + v'), and
// u'_new = log2(mu+1e-8) - log2(sum_exp + 1e-6) + u'.
constexpr float SF      = 14.426950408889634f;   // log2(e)/0.1
constexpr float TWO_SF  = 28.853900817779268f;
constexpr float LOG2MU  = -10.99997045f;         // log2(1/2048 + 1e-8)
constexpr float ERRTHR  = 5.770780163555854f;    // 0.1 * B * S  (err' = S*B*err_ref)

struct Ws {
  float4 YQ4[ROWS];      // (2S*y, v' - S*|y|^2)
  float4 XP4[ROWS];      // (2S*x, u' - S*|x|^2)
  float  varr[ROWS];     // v' (scaled), needed by epilogue
  float  err_w[2048];    // per-wave sum of |du'| over its 4 rows
  float  partials[512];  // per-block cost partials
  int    done;
};

// One persistent cooperative kernel: init -> (u-phase, sync, v-phase+conv,
// sync) x <=100 -> pi/C/cost epilogue. 512 blocks x 256 threads = 2048
// waves; each wave owns 4 consecutive rows (same batch) on BOTH sides.
// u',v' for owned rows live in registers across all iterations; the float4
// tables in ws are the cross-wave communication surface.
__global__ __launch_bounds__(256, 2) void k_sinkhorn(
    const float* __restrict__ x, const float* __restrict__ y,
    float* __restrict__ out, Ws* __restrict__ ws)
{
  cg::grid_group grid = cg::this_grid();
  __shared__ float lred[256];

  const int tid  = (int)(blockIdx.x * 256 + threadIdx.x);  // 0..131071
  const int wave = tid >> 6;                               // 0..2047
  const int lane = (int)(threadIdx.x & 63);
  const int widx = (int)(threadIdx.x >> 6);                // wave-in-block 0..3
  const int r0   = wave * 4;
  const int b    = r0 >> 11;

  // ---- init: build tables (one row per thread for tid<8192) ----
  if (tid < ROWS) {
    int r = tid;
    float x0 = x[3*r], x1 = x[3*r+1], x2 = x[3*r+2];
    float y0 = y[3*r], y1 = y[3*r+1], y2 = y[3*r+2];
    float nx = fmaf(x0, x0, fmaf(x1, x1, x2*x2));
    float ny = fmaf(y0, y0, fmaf(y1, y1, y2*y2));
    ws->XP4[r] = make_float4(TWO_SF*x0, TWO_SF*x1, TWO_SF*x2, -SF*nx);
    ws->YQ4[r] = make_float4(TWO_SF*y0, TWO_SF*y1, TWO_SF*y2, -SF*ny);
    ws->varr[r] = 0.f;
  }
  if (tid == 0) ws->done = 0;

  // ---- per-wave row constants (registers, fixed across iterations) ----
  const float* px = x + (size_t)r0 * 3;
  const float* py = y + (size_t)r0 * 3;
  float xa[4][3], ya[4][3], snx[4], sny[4];
  #pragma unroll
  for (int r = 0; r < 4; ++r) {
    xa[r][0] = px[3*r]; xa[r][1] = px[3*r+1]; xa[r][2] = px[3*r+2];
    ya[r][0] = py[3*r]; ya[r][1] = py[3*r+1]; ya[r][2] = py[3*r+2];
    snx[r] = SF * fmaf(xa[r][0], xa[r][0], fmaf(xa[r][1], xa[r][1], xa[r][2]*xa[r][2]));
    sny[r] = SF * fmaf(ya[r][0], ya[r][0], fmaf(ya[r][1], ya[r][1], ya[r][2]*ya[r][2]));
  }
  float up[4] = {0.f, 0.f, 0.f, 0.f};   // u' for owned x-rows
  float vp[4] = {0.f, 0.f, 0.f, 0.f};   // v' for owned y-rows

  grid.sync();

  const float4* __restrict__ Yb = ws->YQ4 + (size_t)b * NN;
  const float4* __restrict__ Xb = ws->XP4 + (size_t)b * NN;

  for (int it = 0; it < 100; ++it) {
    // ---- u-phase: update owned x-rows from YQ4 ----
    {
      float P0 = up[0]-snx[0], P1 = up[1]-snx[1], P2 = up[2]-snx[2], P3 = up[3]-snx[3];
      float s0 = 0.f, s1 = 0.f, s2 = 0.f, s3 = 0.f;
      #pragma unroll 4
      for (int j = lane; j < NN; j += 64) {
        float4 Y = Yb[j];
        s0 += __builtin_amdgcn_exp2f(fmaf(xa[0][0], Y.x, fmaf(xa[0][1], Y.y, fmaf(xa[0][2], Y.z, Y.w + P0))));
        s1 += __builtin_amdgcn_exp2f(fmaf(xa[1][0], Y.x, fmaf(xa[1][1], Y.y, fmaf(xa[1][2], Y.z, Y.w + P1))));
        s2 += __builtin_amdgcn_exp2f(fmaf(xa[2][0], Y.x, fmaf(xa[2][1], Y.y, fmaf(xa[2][2], Y.z, Y.w + P2))));
        s3 += __builtin_amdgcn_exp2f(fmaf(xa[3][0], Y.x, fmaf(xa[3][1], Y.y, fmaf(xa[3][2], Y.z, Y.w + P3))));
      }
      #pragma unroll
      for (int off = 32; off; off >>= 1) {
        s0 += __shfl_xor(s0, off); s1 += __shfl_xor(s1, off);
        s2 += __shfl_xor(s2, off); s3 += __shfl_xor(s3, off);
      }
      // all lanes compute identically (s uniform post-butterfly)
      float un0 = LOG2MU - __log2f(s0 + 1e-6f) + up[0];
      float un1 = LOG2MU - __log2f(s1 + 1e-6f) + up[1];
      float un2 = LOG2MU - __log2f(s2 + 1e-6f) + up[2];
      float un3 = LOG2MU - __log2f(s3 + 1e-6f) + up[3];
      float derr = fabsf(un0-up[0]) + fabsf(un1-up[1]) + fabsf(un2-up[2]) + fabsf(un3-up[3]);
      up[0] = un0; up[1] = un1; up[2] = un2; up[3] = un3;
      if (lane == 0) {
        ws->XP4[r0+0].w = un0 - snx[0];
        ws->XP4[r0+1].w = un1 - snx[1];
        ws->XP4[r0+2].w = un2 - snx[2];
        ws->XP4[r0+3].w = un3 - snx[3];
        ws->err_w[wave] = derr;
      }
    }
    grid.sync();

    // ---- v-phase: update owned y-rows from XP4 (holds u_new) ----
    {
      float Q0 = vp[0]-sny[0], Q1 = vp[1]-sny[1], Q2 = vp[2]-sny[2], Q3 = vp[3]-sny[3];
      float s0 = 0.f, s1 = 0.f, s2 = 0.f, s3 = 0.f;
      #pragma unroll 4
      for (int j = lane; j < NN; j += 64) {
        float4 X = Xb[j];
        s0 += __builtin_amdgcn_exp2f(fmaf(ya[0][0], X.x, fmaf(ya[0][1], X.y, fmaf(ya[0][2], X.z, X.w + Q0))));
        s1 += __builtin_amdgcn_exp2f(fmaf(ya[1][0], X.x, fmaf(ya[1][1], X.y, fmaf(ya[1][2], X.z, X.w + Q1))));
        s2 += __builtin_amdgcn_exp2f(fmaf(ya[2][0], X.x, fmaf(ya[2][1], X.y, fmaf(ya[2][2], X.z, X.w + Q2))));
        s3 += __builtin_amdgcn_exp2f(fmaf(ya[3][0], X.x, fmaf(ya[3][1], X.y, fmaf(ya[3][2], X.z, X.w + Q3))));
      }
      #pragma unroll
      for (int off = 32; off; off >>= 1) {
        s0 += __shfl_xor(s0, off); s1 += __shfl_xor(s1, off);
        s2 += __shfl_xor(s2, off); s3 += __shfl_xor(s3, off);
      }
      float vn0 = LOG2MU - __log2f(s0 + 1e-6f) + vp[0];
      float vn1 = LOG2MU - __log2f(s1 + 1e-6f) + vp[1];
      float vn2 = LOG2MU - __log2f(s2 + 1e-6f) + vp[2];
      float vn3 = LOG2MU - __log2f(s3 + 1e-6f) + vp[3];
      vp[0] = vn0; vp[1] = vn1; vp[2] = vn2; vp[3] = vn3;
      if (lane == 0) {
        ws->YQ4[r0+0].w = vn0 - sny[0];
        ws->YQ4[r0+1].w = vn1 - sny[1];
        ws->YQ4[r0+2].w = vn2 - sny[2];
        ws->YQ4[r0+3].w = vn3 - sny[3];
        ws->varr[r0+0] = vn0; ws->varr[r0+1] = vn1;
        ws->varr[r0+2] = vn2; ws->varr[r0+3] = vn3;
      }
    }
    // convergence decision from this iteration's u-deltas (err_w stable
    // since the mid-iteration sync)
    if (blockIdx.x == 0) {
      float acc = 0.f;
      for (int t = (int)threadIdx.x; t < 2048; t += 256) acc += ws->err_w[t];
      lred[threadIdx.x] = acc;
      __syncthreads();
      for (int st = 128; st; st >>= 1) {
        if ((int)threadIdx.x < st) lred[threadIdx.x] += lred[threadIdx.x + st];
        __syncthreads();
      }
      if (threadIdx.x == 0 && lred[0] < ERRTHR) ws->done = 1;
      __syncthreads();
    }
    grid.sync();
    if (*(volatile int*)&ws->done) break;   // grid-uniform
  }

  // ---- epilogue: pi, C, cost (u', v' final; last writes pre-last-sync) ----
  float* pi_out = out + 1;
  float* C_out  = out + 1 + (size_t)ROWS * NN;
  const float* yb = y + (size_t)b * NN * 3;
  const float* vb = ws->varr + (size_t)b * NN;

  float acc = 0.f;
  #pragma unroll 2
  for (int j = lane; j < NN; j += 64) {
    float y0 = yb[3*j], y1 = yb[3*j+1], y2 = yb[3*j+2];
    float vj = vb[j];
    #pragma unroll
    for (int r = 0; r < 4; ++r) {
      float d0 = xa[r][0]-y0, d1 = xa[r][1]-y1, d2 = xa[r][2]-y2;
      float C  = fmaf(d0, d0, fmaf(d1, d1, d2*d2));
      float pi = __builtin_amdgcn_exp2f(fmaf(-SF, C, up[r] + vj));
      size_t idx = (size_t)(r0 + r) * NN + j;
      pi_out[idx] = pi;
      C_out[idx]  = C;
      acc = fmaf(pi, C, acc);
    }
  }
  #pragma unroll
  for (int off = 32; off; off >>= 1) acc += __shfl_xor(acc, off);
  if (lane == 0) lred[widx] = acc;
  __syncthreads();
  if (threadIdx.x == 0)
    ws->partials[blockIdx.x] = lred[0] + lred[1] + lred[2] + lred[3];
  grid.sync();
  if (blockIdx.x == 0) {
    float a2 = 0.f;
    for (int t = (int)threadIdx.x; t < 512; t += 256) a2 += ws->partials[t];
    lred[threadIdx.x] = a2;
    __syncthreads();
    for (int st = 128; st; st >>= 1) {
      if ((int)threadIdx.x < st) lred[threadIdx.x] += lred[threadIdx.x + st];
      __syncthreads();
    }
    if (threadIdx.x == 0) out[0] = lred[0] * 0.25f;
  }
}

extern "C" void kernel_launch(void* const* d_in, const int* in_sizes, int n_in,
                              void* d_out, int out_size, void* d_ws, size_t ws_size,
                              hipStream_t stream) {
  (void)in_sizes; (void)n_in; (void)out_size; (void)ws_size;
  const float* x = (const float*)d_in[0];
  const float* y = (const float*)d_in[1];
  float* out = (float*)d_out;
  Ws* ws = (Ws*)d_ws;

  void* args[] = { (void*)&x, (void*)&y, (void*)&out, (void*)&ws };
  hipLaunchCooperativeKernel((const void*)k_sinkhorn, dim3(512), dim3(256),
                             args, 0, stream);
}

// Round 12
// 1644.489 us; speedup vs baseline: 7.0104x; 7.0104x over previous
//
#include <hip/hip_runtime.h>
#include <math.h>

#define NN 2048
#define NB 4
#define ROWS (NB*NN)   // 8192

// u' = u*S, v' = v*S, S = log2(e)/eps. exp((-C+u+v)/eps) = exp2(-S*C+u'+v')
// = exp2(2S*x.y + (u'-S|x|^2) + (v'-S|y|^2)).
// u'_new = log2(mu+1e-8) - log2(sum + 1e-6) + u'.
constexpr float SF      = 14.426950408889634f;   // log2(e)/0.1
constexpr float TWO_SF  = 28.853900817779268f;
constexpr float LOG2MU  = -10.99997045f;         // log2(1/2048 + 1e-8)
constexpr float ERRTHR  = 5.770780163555854f;    // 0.1 * B * S (err in u'-units)

struct Ctrl { int done_iter; int cnt; };

// ws layout (bytes):
//   YQ4  [8192 float4] @ 0        (2S*y, v' - S*|y|^2)
//   XP4  [8192 float4] @ 131072   (2S*x, u' - S*|x|^2)
//   uarr [8192 f32]    @ 262144   (u', scaled)
//   varr [8192 f32]    @ 294912   (v', scaled)
//   err_w[2048 f32]    @ 327680   (per-wave sum |du'| over its 4 rows)
//   parts[512  f32]    @ 335872
//   ctrl               @ 337920

// One Sinkhorn half-pass. 256 blocks x 512 threads = 2048 waves; each wave
// owns 4 consecutive rows (same batch). UPASS=1: update u' from YQ4 (at it==0
// builds the Y-table terms from y directly and inits ctrl). UPASS=0: update
// v' from XP4; block 0 reduces err_w and stamps done_iter on convergence.
// Iteration i runs iff done_iter >= i (stamp at i stops i+1 onward), which
// reproduces the reference while-loop's stop-after-body semantics.
template <int UPASS>
__global__ __launch_bounds__(512) void k_pass(
    const float* __restrict__ x, const float* __restrict__ y,
    float4* __restrict__ XP4, float4* __restrict__ YQ4,
    float* __restrict__ uarr, float* __restrict__ varr,
    float* __restrict__ err_w, Ctrl* __restrict__ ctrl, int it)
{
  __shared__ float red[512];
  if (it > 0 && ctrl->done_iter < it) return;

  if (UPASS && it == 0 && blockIdx.x == 0 && threadIdx.x == 0) {
    ctrl->done_iter = 1000;   // init for this replay (ws re-poisoned each run)
    ctrl->cnt = 0;
  }

  const int wave = (int)(blockIdx.x * 8 + (threadIdx.x >> 6)); // 0..2047
  const int lane = (int)(threadIdx.x & 63);
  const int r0 = wave * 4;
  const int b  = r0 >> 11;

  const float* rowc = (UPASS ? x : y) + (size_t)r0 * 3;
  float* pot = UPASS ? uarr : varr;
  float a0[4], a1[4], a2[4], sn[4], po[4];
  #pragma unroll
  for (int r = 0; r < 4; ++r) {
    a0[r] = rowc[3*r]; a1[r] = rowc[3*r+1]; a2[r] = rowc[3*r+2];
    sn[r] = SF * fmaf(a0[r], a0[r], fmaf(a1[r], a1[r], a2[r]*a2[r]));
    po[r] = (it == 0) ? 0.f : pot[r0 + r];
  }
  const float P0 = po[0]-sn[0], P1 = po[1]-sn[1], P2 = po[2]-sn[2], P3 = po[3]-sn[3];
  float s0 = 0.f, s1 = 0.f, s2 = 0.f, s3 = 0.f;

  if (UPASS && it == 0) {
    // inner table not built yet: form terms from y on the fly
    const float* yb = y + (size_t)b * NN * 3;
    #pragma unroll 2
    for (int j = lane; j < NN; j += 64) {
      float y0 = yb[3*j], y1 = yb[3*j+1], y2 = yb[3*j+2];
      float Yx = TWO_SF*y0, Yy = TWO_SF*y1, Yz = TWO_SF*y2;
      float Yw = -SF * fmaf(y0, y0, fmaf(y1, y1, y2*y2));
      s0 += __builtin_amdgcn_exp2f(fmaf(a0[0], Yx, fmaf(a1[0], Yy, fmaf(a2[0], Yz, Yw + P0))));
      s1 += __builtin_amdgcn_exp2f(fmaf(a0[1], Yx, fmaf(a1[1], Yy, fmaf(a2[1], Yz, Yw + P1))));
      s2 += __builtin_amdgcn_exp2f(fmaf(a0[2], Yx, fmaf(a1[2], Yy, fmaf(a2[2], Yz, Yw + P2))));
      s3 += __builtin_amdgcn_exp2f(fmaf(a0[3], Yx, fmaf(a1[3], Yy, fmaf(a2[3], Yz, Yw + P3))));
    }
  } else {
    const float4* __restrict__ T = (UPASS ? YQ4 : XP4) + (size_t)b * NN;
    #pragma unroll 4
    for (int j = lane; j < NN; j += 64) {
      float4 Y = T[j];
      s0 += __builtin_amdgcn_exp2f(fmaf(a0[0], Y.x, fmaf(a1[0], Y.y, fmaf(a2[0], Y.z, Y.w + P0))));
      s1 += __builtin_amdgcn_exp2f(fmaf(a0[1], Y.x, fmaf(a1[1], Y.y, fmaf(a2[1], Y.z, Y.w + P1))));
      s2 += __builtin_amdgcn_exp2f(fmaf(a0[2], Y.x, fmaf(a1[2], Y.y, fmaf(a2[2], Y.z, Y.w + P2))));
      s3 += __builtin_amdgcn_exp2f(fmaf(a0[3], Y.x, fmaf(a1[3], Y.y, fmaf(a2[3], Y.z, Y.w + P3))));
    }
  }
  #pragma unroll
  for (int off = 32; off; off >>= 1) {
    s0 += __shfl_xor(s0, off); s1 += __shfl_xor(s1, off);
    s2 += __shfl_xor(s2, off); s3 += __shfl_xor(s3, off);
  }

  float n0 = LOG2MU - __log2f(s0 + 1e-6f) + po[0];
  float n1 = LOG2MU - __log2f(s1 + 1e-6f) + po[1];
  float n2 = LOG2MU - __log2f(s2 + 1e-6f) + po[2];
  float n3 = LOG2MU - __log2f(s3 + 1e-6f) + po[3];

  if (lane == 0) {
    pot[r0+0] = n0; pot[r0+1] = n1; pot[r0+2] = n2; pot[r0+3] = n3;
    float4* W = UPASS ? XP4 : YQ4;
    if (it == 0) {
      W[r0+0] = make_float4(TWO_SF*a0[0], TWO_SF*a1[0], TWO_SF*a2[0], n0 - sn[0]);
      W[r0+1] = make_float4(TWO_SF*a0[1], TWO_SF*a1[1], TWO_SF*a2[1], n1 - sn[1]);
      W[r0+2] = make_float4(TWO_SF*a0[2], TWO_SF*a1[2], TWO_SF*a2[2], n2 - sn[2]);
      W[r0+3] = make_float4(TWO_SF*a0[3], TWO_SF*a1[3], TWO_SF*a2[3], n3 - sn[3]);
    } else {
      W[r0+0].w = n0 - sn[0]; W[r0+1].w = n1 - sn[1];
      W[r0+2].w = n2 - sn[2]; W[r0+3].w = n3 - sn[3];
    }
    if (UPASS)
      err_w[wave] = fabsf(n0-po[0]) + fabsf(n1-po[1]) + fabsf(n2-po[2]) + fabsf(n3-po[3]);
  }

  if (!UPASS) {
    // convergence decision (err_w complete from this iteration's u-pass)
    __syncthreads();
    if (blockIdx.x == 0) {
      float acc = 0.f;
      for (int t = (int)threadIdx.x; t < 2048; t += 512) acc += err_w[t];
      red[threadIdx.x] = acc;
      __syncthreads();
      for (int st = 256; st; st >>= 1) {
        if ((int)threadIdx.x < st) red[threadIdx.x] += red[threadIdx.x + st];
        __syncthreads();
      }
      if (threadIdx.x == 0 && red[0] < ERRTHR && ctrl->done_iter > it)
        ctrl->done_iter = it;
    }
  }
}

__global__ __launch_bounds__(256) void k_final(
    const float* __restrict__ x, const float* __restrict__ y,
    const float* __restrict__ uarr, const float* __restrict__ varr,
    float* __restrict__ out, float* __restrict__ partials,
    Ctrl* __restrict__ ctrl)
{
  __shared__ float bred[4];
  __shared__ int islast;
  const int wave = (int)(blockIdx.x * 4 + (threadIdx.x >> 6)); // 0..2047
  const int lane = (int)(threadIdx.x & 63);
  const int widx = (int)(threadIdx.x >> 6);
  const int r0 = wave * 4;
  const int b  = r0 >> 11;

  float* pi_out = out + 1;
  float* C_out  = out + 1 + (size_t)ROWS * NN;

  const float* xr = x + (size_t)r0 * 3;
  float a0[4], a1[4], a2[4], up[4];
  #pragma unroll
  for (int r = 0; r < 4; ++r) {
    a0[r] = xr[3*r]; a1[r] = xr[3*r+1]; a2[r] = xr[3*r+2];
    up[r] = uarr[r0 + r];
  }
  const float* yb = y + (size_t)b * NN * 3;
  const float* vb = varr + (size_t)b * NN;

  float acc = 0.f;
  #pragma unroll 2
  for (int j = lane; j < NN; j += 64) {
    float y0 = yb[3*j], y1 = yb[3*j+1], y2 = yb[3*j+2];
    float vj = vb[j];
    #pragma unroll
    for (int r = 0; r < 4; ++r) {
      float d0 = a0[r]-y0, d1 = a1[r]-y1, d2 = a2[r]-y2;
      float C  = fmaf(d0, d0, fmaf(d1, d1, d2*d2));
      float pi = __builtin_amdgcn_exp2f(fmaf(-SF, C, up[r] + vj));
      size_t idx = (size_t)(r0 + r) * NN + j;
      pi_out[idx] = pi;
      C_out[idx]  = C;
      acc = fmaf(pi, C, acc);
    }
  }
  #pragma unroll
  for (int off = 32; off; off >>= 1) acc += __shfl_xor(acc, off);
  if (lane == 0) bred[widx] = acc;
  __syncthreads();
  if (threadIdx.x == 0) {
    partials[blockIdx.x] = bred[0] + bred[1] + bred[2] + bred[3];
    __threadfence();   // release: partial visible before count increment
    islast = (atomicAdd(&ctrl->cnt, 1) == 511);
  }
  __syncthreads();
  if (islast) {
    __threadfence();   // acquire: all partials visible
    float a = 0.f;
    for (int t = (int)threadIdx.x; t < 512; t += 256) a += partials[t];
    #pragma unroll
    for (int off = 32; off; off >>= 1) a += __shfl_xor(a, off);
    if (lane == 0) bred[widx] = a;
    __syncthreads();
    if (threadIdx.x == 0)
      out[0] = (bred[0] + bred[1] + bred[2] + bred[3]) * 0.25f;
  }
}

extern "C" void kernel_launch(void* const* d_in, const int* in_sizes, int n_in,
                              void* d_out, int out_size, void* d_ws, size_t ws_size,
                              hipStream_t stream) {
  (void)in_sizes; (void)n_in; (void)out_size; (void)ws_size;
  const float* x = (const float*)d_in[0];
  const float* y = (const float*)d_in[1];
  float* out = (float*)d_out;

  char* ws = (char*)d_ws;
  float4* YQ4  = (float4*)(ws + 0);
  float4* XP4  = (float4*)(ws + 131072);
  float* uarr  = (float*)(ws + 262144);
  float* varr  = (float*)(ws + 294912);
  float* err_w = (float*)(ws + 327680);
  float* parts = (float*)(ws + 335872);
  Ctrl*  ctrl  = (Ctrl*)(ws + 337920);

  for (int it = 0; it < 100; ++it) {
    k_pass<1><<<256, 512, 0, stream>>>(x, y, XP4, YQ4, uarr, varr, err_w, ctrl, it);
    k_pass<0><<<256, 512, 0, stream>>>(x, y, XP4, YQ4, uarr, varr, err_w, ctrl, it);
  }
  k_final<<<512, 256, 0, stream>>>(x, y, uarr, varr, out, parts, ctrl);
}